// Round 15
// baseline (364.820 us; speedup 1.0000x reference)
//
#include <hip/hip_runtime.h>
#include <stdint.h>

#define B_ 2
#define N_ 2048
#define C_ 512
#define H_ 8
#define D_ 64
#define TOPK_ 100
#define BN_ (B_*N_)
#define CAP_ 256

typedef __attribute__((ext_vector_type(8))) short s16x8;
typedef __attribute__((ext_vector_type(8))) unsigned short u16x8;
typedef __attribute__((ext_vector_type(4))) float f32x4;

__device__ __forceinline__ int mbcnt64(unsigned long long m) {
  return __builtin_amdgcn_mbcnt_hi((unsigned)(m >> 32),
         __builtin_amdgcn_mbcnt_lo((unsigned)m, 0u));
}
// order-preserving f32 <-> u32 bijection (exact roundtrip; r10-r14 proven)
__device__ __forceinline__ float u2f(unsigned uu) {
  unsigned bits = (uu & 0x80000000u) ? (uu ^ 0x80000000u) : ~uu;
  return __uint_as_float(bits);
}
__device__ __forceinline__ unsigned short bf16rn(float x) {
  unsigned u = __float_as_uint(x);
  unsigned r = (u + 0x7fffu + ((u >> 16) & 1u)) >> 16;
  return (unsigned short)r;
}
__device__ __forceinline__ float bf16f(unsigned short h) {
  return __uint_as_float(((unsigned)h) << 16);
}
__device__ __forceinline__ void split3(float x, unsigned short& h,
                                       unsigned short& m, unsigned short& l) {
  h = bf16rn(x);
  float r1 = x - bf16f(h);
  m = bf16rn(r1);
  float r2 = r1 - bf16f(m);
  l = bf16rn(r2);
}
#define SWZ(r, sl) (((sl) ^ (((r) >> 1) & 3)) << 3)
#define MFMA_BF16(a, b, c) __builtin_amdgcn_mfma_f32_16x16x32_bf16(a, b, c, 0, 0, 0)
#define SIX_PASS(acc, ah, am, al, bh, bm, bl) \
  do { \
    acc = MFMA_BF16(ah, bl, acc); \
    acc = MFMA_BF16(am, bm, acc); \
    acc = MFMA_BF16(al, bh, acc); \
    acc = MFMA_BF16(ah, bm, acc); \
    acc = MFMA_BF16(am, bh, acc); \
    acc = MFMA_BF16(ah, bh, acc); \
  } while (0)

// ---- split weights (Wv, Wp) into 3 bf16 planes each ----
__global__ __launch_bounds__(256)
void wsplit(const float* __restrict__ W0, const float* __restrict__ W1,
            unsigned short* __restrict__ Wsp)
{
  int z = blockIdx.y;
  const float* W = (z == 0) ? W0 : W1;
  const size_t WN = (size_t)C_ * C_;
  unsigned short* Wh = Wsp + (size_t)z * 3 * WN;
  unsigned short* Wm = Wh + WN;
  unsigned short* Wl = Wh + 2 * WN;
  int i = blockIdx.x * 256 + threadIdx.x;
  unsigned short h, m, l;
  split3(W[i], h, m, l);
  Wh[i] = h; Wm[i] = m; Wl[i] = l;
}

// ---- EXACT f32 64x64 GEMM for qh/kh (r7-proven: 74 us, occ 32%) ----
// NUMERICS CONTRACT: per output, strictly k-ascending single-acc fmaf chain
// (k=0..511), bias added once at the end — bit-identical to r6-r14.
// (r12's 128x64 8x4-micro retile regressed: grid 512 -> 2 blocks/CU capped
// occupancy at 19%; occupancy beats per-wave LDS efficiency here.)
__global__ __launch_bounds__(256)
void gemm64(const float* __restrict__ X0, const float* __restrict__ X1,
            const float* __restrict__ W0, const float* __restrict__ W1,
            const float* __restrict__ b0, const float* __restrict__ b1,
            float* __restrict__ O0, float* __restrict__ O1)
{
  int z = blockIdx.z;
  const float* X = (z == 0) ? X0 : X1;
  const float* W = (z == 0) ? W0 : W1;
  const float* bs = (z == 0) ? b0 : b1;
  float* O = (z == 0) ? O0 : O1;

  __shared__ float Xs[32][68];
  __shared__ float Ws[32][68];

  int t = threadIdx.x;
  int tr = t >> 4, tc = t & 15;
  int m0 = blockIdx.x * 64, c0 = blockIdx.y * 64;

  float acc[4][4] = {};

  for (int k0 = 0; k0 < C_; k0 += 32) {
    #pragma unroll
    for (int j2 = 0; j2 < 2; ++j2) {
      int fid = t + j2 * 256;
      int row = fid >> 3;
      int dk  = (fid & 7) << 2;
      float4 xv = *(const float4*)(X + (size_t)(m0 + row) * C_ + k0 + dk);
      Xs[dk+0][row] = xv.x; Xs[dk+1][row] = xv.y; Xs[dk+2][row] = xv.z; Xs[dk+3][row] = xv.w;
      float4 wv = *(const float4*)(W + (size_t)(c0 + row) * C_ + k0 + dk);
      Ws[dk+0][row] = wv.x; Ws[dk+1][row] = wv.y; Ws[dk+2][row] = wv.z; Ws[dk+3][row] = wv.w;
    }
    __syncthreads();
    #pragma unroll
    for (int k = 0; k < 32; ++k) {
      float4 a = *(const float4*)&Xs[k][tr << 2];
      float4 b = *(const float4*)&Ws[k][tc << 2];
      float ar[4] = {a.x, a.y, a.z, a.w};
      float br[4] = {b.x, b.y, b.z, b.w};
      #pragma unroll
      for (int i = 0; i < 4; ++i)
        #pragma unroll
        for (int j = 0; j < 4; ++j)
          acc[i][j] = fmaf(ar[i], br[j], acc[i][j]);
    }
    __syncthreads();
  }

  float bv[4];
  #pragma unroll
  for (int j = 0; j < 4; ++j) bv[j] = bs[c0 + (tc << 2) + j];

  #pragma unroll
  for (int i = 0; i < 4; ++i) {
    float4 o = make_float4(acc[i][0] + bv[0], acc[i][1] + bv[1],
                           acc[i][2] + bv[2], acc[i][3] + bv[3]);
    int m = m0 + (tr << 2) + i;
    int bb = m >> 11;
    int tok = m & (N_ - 1);
    int h = blockIdx.y;
    *(float4*)(O + (((size_t)(bb * H_ + h) * N_) + tok) * D_ + (tc << 2)) = o;
  }
}

// ---- bf16x3 6-pass MFMA GEMM (vh & final proj; post-select paths) ----
__global__ __launch_bounds__(256)
void gemm_mfma(const float* __restrict__ A,
               const unsigned short* __restrict__ Wplanes,
               const float* __restrict__ bias,
               float* __restrict__ O, int scatter)
{
  const size_t WN = (size_t)C_ * C_;
  const unsigned short* Wh = Wplanes;
  const unsigned short* Wm = Wplanes + WN;
  const unsigned short* Wl = Wplanes + 2 * WN;

  __shared__ unsigned short Ah[128][32], Am[128][32], Al[128][32];
  __shared__ unsigned short Bh[64][32],  Bm[64][32],  Bl[64][32];

  int t = threadIdx.x;
  int l = t & 63, wv = t >> 6;
  int wm = wv >> 1, wn = wv & 1;
  int m0 = blockIdx.x * 128, n0 = blockIdx.y * 64;

  f32x4 acc[4][2];
  #pragma unroll
  for (int i = 0; i < 4; ++i)
    #pragma unroll
    for (int j = 0; j < 2; ++j) acc[i][j] = (f32x4){0.f,0.f,0.f,0.f};

  for (int k0 = 0; k0 < C_; k0 += 32) {
    #pragma unroll
    for (int sj = 0; sj < 2; ++sj) {
      int s = t + sj * 256;
      int r = s >> 2, sl = s & 3, c = sl << 3;
      int co = SWZ(r, sl);
      const float* src = A + (size_t)(m0 + r) * C_ + k0 + c;
      float4 x0 = *(const float4*)src;
      float4 x1 = *(const float4*)(src + 4);
      float xs[8] = {x0.x,x0.y,x0.z,x0.w,x1.x,x1.y,x1.z,x1.w};
      unsigned short hv[8], mv[8], lv[8];
      #pragma unroll
      for (int j = 0; j < 8; ++j) split3(xs[j], hv[j], mv[j], lv[j]);
      *(s16x8*)&Ah[r][co] = *(s16x8*)hv;
      *(s16x8*)&Am[r][co] = *(s16x8*)mv;
      *(s16x8*)&Al[r][co] = *(s16x8*)lv;
    }
    {
      int r = t >> 2, sl = t & 3, c = sl << 3;
      int co = SWZ(r, sl);
      size_t boff = (size_t)(n0 + r) * C_ + k0 + c;
      *(s16x8*)&Bh[r][co] = *(const s16x8*)&Wh[boff];
      *(s16x8*)&Bm[r][co] = *(const s16x8*)&Wm[boff];
      *(s16x8*)&Bl[r][co] = *(const s16x8*)&Wl[boff];
    }
    __syncthreads();

    int lr = l & 15, s0 = l >> 4;
    s16x8 ah[4], am[4], al[4];
    #pragma unroll
    for (int mi = 0; mi < 4; ++mi) {
      int R = wm*64 + mi*16 + lr;
      int co = SWZ(R, s0);
      ah[mi] = *(const s16x8*)&Ah[R][co];
      am[mi] = *(const s16x8*)&Am[R][co];
      al[mi] = *(const s16x8*)&Al[R][co];
    }
    #pragma unroll
    for (int nj = 0; nj < 2; ++nj) {
      int Rb = wn*32 + nj*16 + lr;
      int co = SWZ(Rb, s0);
      s16x8 bh = *(const s16x8*)&Bh[Rb][co];
      s16x8 bm = *(const s16x8*)&Bm[Rb][co];
      s16x8 bl = *(const s16x8*)&Bl[Rb][co];
      #pragma unroll
      for (int mi = 0; mi < 4; ++mi)
        SIX_PASS(acc[mi][nj], ah[mi], am[mi], al[mi], bh, bm, bl);
    }
    __syncthreads();
  }

  int lr = l & 15, lq = l >> 4;
  #pragma unroll
  for (int mi = 0; mi < 4; ++mi) {
    #pragma unroll
    for (int nj = 0; nj < 2; ++nj) {
      #pragma unroll
      for (int r = 0; r < 4; ++r) {
        int m = m0 + wm*64 + mi*16 + lq*4 + r;
        int c = n0 + wn*32 + nj*16 + lr;
        float y = acc[mi][nj][r] + bias[c];
        if (scatter) {
          int bb = m >> 11, tok = m & (N_ - 1);
          int hh = c >> 6, d = c & 63;
          O[(((size_t)(bb * H_ + hh) * N_) + tok) * D_ + d] = y;
        } else {
          O[(size_t)m * C_ + c] = y;
        }
      }
    }
  }
}

// ---- EXACT f32 QK^T: 128x128 tile, 8x8 micro (r7/r11-r14 proven) ----
__global__ __launch_bounds__(256)
void qk128(const float* __restrict__ qh, const float* __restrict__ kh,
           float* __restrict__ S, int slice0, int row0, int Rrows)
{
  int z = blockIdx.z;
  int slice = slice0 + z;
  const float* Q = qh + (size_t)slice * N_ * D_;
  const float* K = kh + (size_t)slice * N_ * D_;
  float* Sp = S + (size_t)z * Rrows * N_;

  __shared__ float Qs[32][132];
  __shared__ float Ks[32][132];

  int t = threadIdx.x;
  int tr = t >> 4, tc = t & 15;
  int n0 = blockIdx.x * 128, m0 = blockIdx.y * 128;

  float acc[2][2][4][4] = {};

  #pragma unroll
  for (int k0 = 0; k0 < D_; k0 += 32) {
    #pragma unroll
    for (int jj = 0; jj < 4; ++jj) {
      int fid = t + jj * 256;
      int row = fid >> 3;
      int dk  = (fid & 7) << 2;
      float4 qv = *(const float4*)(Q + (size_t)(row0 + n0 + row) * D_ + k0 + dk);
      Qs[dk+0][row] = qv.x; Qs[dk+1][row] = qv.y; Qs[dk+2][row] = qv.z; Qs[dk+3][row] = qv.w;
      float4 kv = *(const float4*)(K + (size_t)(m0 + row) * D_ + k0 + dk);
      Ks[dk+0][row] = kv.x; Ks[dk+1][row] = kv.y; Ks[dk+2][row] = kv.z; Ks[dk+3][row] = kv.w;
    }
    __syncthreads();
    #pragma unroll 8
    for (int k = 0; k < 32; ++k) {
      float a[2][4], b[2][4];
      *(float4*)&a[0][0] = *(const float4*)&Qs[k][tr << 2];
      *(float4*)&a[1][0] = *(const float4*)&Qs[k][64 + (tr << 2)];
      *(float4*)&b[0][0] = *(const float4*)&Ks[k][tc << 2];
      *(float4*)&b[1][0] = *(const float4*)&Ks[k][64 + (tc << 2)];
      #pragma unroll
      for (int ia = 0; ia < 2; ++ia)
        #pragma unroll
        for (int ib = 0; ib < 2; ++ib)
          #pragma unroll
          for (int i = 0; i < 4; ++i)
            #pragma unroll
            for (int j = 0; j < 4; ++j)
              acc[ia][ib][i][j] = fmaf(a[ia][i], b[ib][j], acc[ia][ib][i][j]);
    }
    __syncthreads();
  }

  const float scale = 0.125f;
  #pragma unroll
  for (int ia = 0; ia < 2; ++ia)
    #pragma unroll
    for (int i = 0; i < 4; ++i) {
      int n = n0 + ia*64 + (tr << 2) + i;
      #pragma unroll
      for (int ib = 0; ib < 2; ++ib) {
        float4 o = make_float4(acc[ia][ib][i][0] * scale, acc[ia][ib][i][1] * scale,
                               acc[ia][ib][i][2] * scale, acc[ia][ib][i][3] * scale);
        *(float4*)(Sp + (size_t)n * N_ + m0 + ib*64 + (tc << 2)) = o;
      }
    }
}

// ---- one wave per row: TWO-STAGE exact radix-select (r14-proven) ----
__global__ __launch_bounds__(256)
void topk_softmax_pv(const float* __restrict__ S, const float* __restrict__ vh,
                     float* __restrict__ outp, int slice0, int row0, int log2R)
{
  __shared__ float wL[4][CAP_];          // u32 candidate vals, then f32 weights
  __shared__ unsigned short iL[4][CAP_]; // col indices

  int t = threadIdx.x;
  int wv = t >> 6;
  int lane = t & 63;
  int gr = blockIdx.x * 4 + wv;
  int s_local = gr >> log2R;
  int rrow = gr & ((1 << log2R) - 1);
  int slice = slice0 + s_local;
  int row = row0 + rrow;

  const float* Srow = S + ((size_t)gr) * N_;

  unsigned u[32];
  #pragma unroll
  for (int i = 0; i < 8; ++i) {
    float4 v = *(const float4*)(Srow + i * 256 + lane * 4);
    float xv[4] = {v.x, v.y, v.z, v.w};
    #pragma unroll
    for (int c = 0; c < 4; ++c) {
      unsigned bits = __float_as_uint(xv[c]);
      u[i*4+c] = bits ^ ((unsigned)(((int)bits) >> 31) | 0x80000000u);
    }
  }

  unsigned mxu = 0u;
  #pragma unroll
  for (int i = 0; i < 32; ++i) mxu = (u[i] > mxu) ? u[i] : mxu;
  #pragma unroll
  for (int off = 32; off >= 1; off >>= 1) {
    unsigned o = (unsigned)__shfl_xor((int)mxu, off);
    mxu = (o > mxu) ? o : mxu;
  }
  unsigned mxs = (unsigned)__builtin_amdgcn_readfirstlane((int)mxu);
  float mx = u2f(mxs);

  unsigned* uList = (unsigned*)&wL[wv][0];
  const float* Vs = vh + (size_t)slice * N_ * D_;

  // ---- Phase A: full scans until success count lands in (TOPK, CAP] ----
  unsigned thr = 0u;
  int cnt = -1;
  int bitResume = -1;
  for (int bit = 31; bit >= 0; --bit) {
    unsigned cand = thr | (1u << bit);
    if (cand > mxs) continue;
    int c = 0;
    #pragma unroll
    for (int i = 0; i < 32; ++i) c += (u[i] >= cand) ? 1 : 0;
    #pragma unroll
    for (int off = 32; off >= 1; off >>= 1) c += __shfl_xor(c, off);
    if (c >= TOPK_) {
      thr = cand;
      if (c == TOPK_) break;
      if (c <= CAP_) { cnt = c; bitResume = bit - 1; break; }
    }
  }

  float s = 0.f;
  int total = 0;

  if (cnt >= 0) {
    // compact candidates (u >= thr) to LDS, (i,lane) order
    int base = 0;
    #pragma unroll
    for (int i = 0; i < 32; ++i) {
      bool kp = (u[i] >= thr);
      unsigned long long m = __ballot(kp);
      if (kp) {
        int pos = base + mbcnt64(m);
        uList[pos] = u[i];
        iL[wv][pos] = (unsigned short)(((i >> 2) << 8) + (lane << 2) + (i & 3));
      }
      base += __popcll(m);
    }
    // ---- Phase B: refine over the list (<=4 entries/lane) ----
    for (int bit = bitResume; bit >= 0; --bit) {
      unsigned cand = thr | (1u << bit);
      if (cand > mxs) continue;
      int c = 0;
      for (int e = lane; e < cnt; e += 64) c += (uList[e] >= cand) ? 1 : 0;
      #pragma unroll
      for (int off = 32; off >= 1; off >>= 1) c += __shfl_xor(c, off);
      if (c >= TOPK_) {
        thr = cand;
        if (c == TOPK_) break;
      }
    }
    // ---- stable final extraction from the list ----
    int base2 = 0;
    for (int e0 = 0; e0 < cnt; e0 += 64) {
      int e = e0 + lane;
      bool valid = (e < cnt);
      unsigned uv = valid ? uList[e] : 0u;
      unsigned short ix = valid ? iL[wv][e] : (unsigned short)0;
      bool kp = valid && (uv >= thr);
      float ev = kp ? __expf(u2f(uv) - mx) : 0.f;
      s += ev;
      unsigned long long m = __ballot(kp);
      if (kp) {
        int pos = base2 + mbcnt64(m);
        wL[wv][pos] = ev;
        iL[wv][pos] = ix;
      }
      base2 += __popcll(m);
    }
    total = base2;
  } else {
    // fallback (early c==TOPK exit or tie-heavy rows): register path (r13)
    int base = 0;
    #pragma unroll
    for (int i = 0; i < 32; ++i) {
      bool kp = (u[i] >= thr);
      unsigned long long m = __ballot(kp);
      float ev = kp ? __expf(u2f(u[i]) - mx) : 0.f;
      s += ev;
      if (kp) {
        int pos = base + mbcnt64(m);
        if (pos < CAP_) {
          wL[wv][pos] = ev;
          iL[wv][pos] = (unsigned short)(((i >> 2) << 8) + (lane << 2) + (i & 3));
        }
      }
      base += __popcll(m);
    }
    total = base < CAP_ ? base : CAP_;
  }

  #pragma unroll
  for (int off = 32; off >= 1; off >>= 1) s += __shfl_xor(s, off);
  float inv = 1.f / s;

  // gather-PV, 8-deep ILP, vectorized list reads; normalize once at end
  float a0=0.f,a1=0.f,a2=0.f,a3=0.f,a4=0.f,a5=0.f,a6=0.f,a7=0.f;
  int e = 0;
  for (; e + 8 <= total; e += 8) {
    float4 wa = *(const float4*)&wL[wv][e];
    float4 wb = *(const float4*)&wL[wv][e+4];
    u16x8 jj = *(const u16x8*)&iL[wv][e];
    float v0=Vs[(size_t)jj[0]*D_+lane], v1=Vs[(size_t)jj[1]*D_+lane];
    float v2=Vs[(size_t)jj[2]*D_+lane], v3=Vs[(size_t)jj[3]*D_+lane];
    float v4=Vs[(size_t)jj[4]*D_+lane], v5=Vs[(size_t)jj[5]*D_+lane];
    float v6=Vs[(size_t)jj[6]*D_+lane], v7=Vs[(size_t)jj[7]*D_+lane];
    a0 = fmaf(wa.x, v0, a0); a1 = fmaf(wa.y, v1, a1);
    a2 = fmaf(wa.z, v2, a2); a3 = fmaf(wa.w, v3, a3);
    a4 = fmaf(wb.x, v4, a4); a5 = fmaf(wb.y, v5, a5);
    a6 = fmaf(wb.z, v6, a6); a7 = fmaf(wb.w, v7, a7);
  }
  for (; e < total; ++e)
    a0 = fmaf(wL[wv][e], Vs[(size_t)iL[wv][e] * D_ + lane], a0);
  float acc = (((a0 + a1) + (a2 + a3)) + ((a4 + a5) + (a6 + a7))) * inv;

  int b = slice >> 3;
  int h = slice & 7;
  outp[((size_t)(b * N_ + row)) * C_ + h * D_ + lane] = acc;
}

extern "C" void kernel_launch(void* const* d_in, const int* in_sizes, int n_in,
                              void* d_out, int out_size, void* d_ws, size_t ws_size,
                              hipStream_t stream) {
  const float* q  = (const float*)d_in[0];
  const float* k  = (const float*)d_in[1];
  const float* v  = (const float*)d_in[2];
  const float* Wq = (const float*)d_in[3];
  const float* bq = (const float*)d_in[4];
  const float* Wk = (const float*)d_in[5];
  const float* bk = (const float*)d_in[6];
  const float* Wv = (const float*)d_in[7];
  const float* bv = (const float*)d_in[8];
  const float* Wp = (const float*)d_in[9];
  const float* bp = (const float*)d_in[10];

  const size_t NB = (size_t)B_ * H_ * N_ * D_;   // 2,097,152 floats
  const size_t WN = (size_t)C_ * C_;
  float* qh  = (float*)d_ws;
  float* kh  = qh + NB;
  float* vh  = kh + NB;
  float* pre = vh + NB;
  unsigned short* Wsp = (unsigned short*)(pre + NB);   // 2 x 3 x WN u16
  float* S   = (float*)(Wsp + 2 * 3 * WN);

  size_t fixedB = 4 * NB * 4 + 2 * 3 * WN * 2;         // ~35.1 MB
  size_t sliceB = (size_t)N_ * N_ * 4;                 // 16.78 MB
  size_t avail = (ws_size > fixedB) ? ws_size - fixedB : 0;

  // ns capped at 8: S chunk = 134 MB stays L3-resident (ns=16's 268 MB
  // spilled -> topk read 82 MB/dispatch from HBM at 1050 GB/s, r13 PMC)
  int ns = 1, R = 2048;
  if      (avail >= 8 * sliceB)  { ns = 8;  R = 2048; }
  else if (avail >= 4 * sliceB)  { ns = 4;  R = 2048; }
  else if (avail >= 2 * sliceB)  { ns = 2;  R = 2048; }
  else if (avail >= 1 * sliceB)  { ns = 1;  R = 2048; }
  else if (avail >= sliceB / 2)  { ns = 1;  R = 1024; }
  else                           { ns = 1;  R = 512;  }
  int log2R = (R == 2048) ? 11 : ((R == 1024) ? 10 : 9);

  dim3 blk(256);

  // weight splits for the two MFMA GEMMs (Wv, Wp)
  wsplit<<<dim3(WN / 256, 2), blk, 0, stream>>>(Wv, Wp, Wsp);

  // q,k projections: EXACT f32 chain, head-scatter
  gemm64<<<dim3(BN_/64, C_/64, 2), blk, 0, stream>>>(
      q, k, Wq, Wk, bq, bk, qh, kh);

  // v projection: bf16x3 6-pass MFMA (post-select path), head-scatter
  gemm_mfma<<<dim3(BN_/128, C_/64), blk, 0, stream>>>(
      v, Wsp, bv, vh, 1);

  for (int s0 = 0; s0 < B_ * H_; s0 += ns) {
    int cur = (B_ * H_ - s0) < ns ? (B_ * H_ - s0) : ns;
    for (int r0 = 0; r0 < N_; r0 += R) {
      qk128<<<dim3(R/128, N_/128, cur), blk, 0, stream>>>(qh, kh, S, s0, r0, R);
      topk_softmax_pv<<<dim3(cur * (R/4)), blk, 0, stream>>>(S, vh, pre, s0, r0, log2R);
    }
  }

  // final projection: bf16x3 6-pass MFMA -> d_out
  gemm_mfma<<<dim3(BN_/128, C_/64), blk, 0, stream>>>(
      pre, Wsp + 3 * WN, bp, (float*)d_out, 0);
}

// Round 16
// 342.529 us; speedup vs baseline: 1.0651x; 1.0651x over previous
//
#include <hip/hip_runtime.h>
#include <stdint.h>

#define B_ 2
#define N_ 2048
#define C_ 512
#define H_ 8
#define D_ 64
#define TOPK_ 100
#define BN_ (B_*N_)
#define CAP_ 256

typedef __attribute__((ext_vector_type(8))) short s16x8;
typedef __attribute__((ext_vector_type(8))) unsigned short u16x8;
typedef __attribute__((ext_vector_type(4))) float f32x4;

__device__ __forceinline__ int mbcnt64(unsigned long long m) {
  return __builtin_amdgcn_mbcnt_hi((unsigned)(m >> 32),
         __builtin_amdgcn_mbcnt_lo((unsigned)m, 0u));
}
// order-preserving f32 <-> u32 bijection (exact roundtrip; r10-r15 proven)
__device__ __forceinline__ float u2f(unsigned uu) {
  unsigned bits = (uu & 0x80000000u) ? (uu ^ 0x80000000u) : ~uu;
  return __uint_as_float(bits);
}
__device__ __forceinline__ unsigned short bf16rn(float x) {
  unsigned u = __float_as_uint(x);
  unsigned r = (u + 0x7fffu + ((u >> 16) & 1u)) >> 16;
  return (unsigned short)r;
}
__device__ __forceinline__ float bf16f(unsigned short h) {
  return __uint_as_float(((unsigned)h) << 16);
}
__device__ __forceinline__ void split3(float x, unsigned short& h,
                                       unsigned short& m, unsigned short& l) {
  h = bf16rn(x);
  float r1 = x - bf16f(h);
  m = bf16rn(r1);
  float r2 = r1 - bf16f(m);
  l = bf16rn(r2);
}
#define SWZ(r, sl) (((sl) ^ (((r) >> 1) & 3)) << 3)
#define MFMA_BF16(a, b, c) __builtin_amdgcn_mfma_f32_16x16x32_bf16(a, b, c, 0, 0, 0)
#define SIX_PASS(acc, ah, am, al, bh, bm, bl) \
  do { \
    acc = MFMA_BF16(ah, bl, acc); \
    acc = MFMA_BF16(am, bm, acc); \
    acc = MFMA_BF16(al, bh, acc); \
    acc = MFMA_BF16(ah, bm, acc); \
    acc = MFMA_BF16(am, bh, acc); \
    acc = MFMA_BF16(ah, bh, acc); \
  } while (0)

// ---- split weights (Wv, Wp) into 3 bf16 planes each ----
__global__ __launch_bounds__(256)
void wsplit(const float* __restrict__ W0, const float* __restrict__ W1,
            unsigned short* __restrict__ Wsp)
{
  int z = blockIdx.y;
  const float* W = (z == 0) ? W0 : W1;
  const size_t WN = (size_t)C_ * C_;
  unsigned short* Wh = Wsp + (size_t)z * 3 * WN;
  unsigned short* Wm = Wh + WN;
  unsigned short* Wl = Wh + 2 * WN;
  int i = blockIdx.x * 256 + threadIdx.x;
  unsigned short h, m, l;
  split3(W[i], h, m, l);
  Wh[i] = h; Wm[i] = m; Wl[i] = l;
}

// ---- EXACT f32 64x64 GEMM for qh/kh (r7-proven) ----
// NUMERICS CONTRACT: per output, strictly k-ascending single-acc fmaf chain
// (k=0..511), bias added once at the end — bit-identical to r6-r15.
__global__ __launch_bounds__(256)
void gemm64(const float* __restrict__ X0, const float* __restrict__ X1,
            const float* __restrict__ W0, const float* __restrict__ W1,
            const float* __restrict__ b0, const float* __restrict__ b1,
            float* __restrict__ O0, float* __restrict__ O1)
{
  int z = blockIdx.z;
  const float* X = (z == 0) ? X0 : X1;
  const float* W = (z == 0) ? W0 : W1;
  const float* bs = (z == 0) ? b0 : b1;
  float* O = (z == 0) ? O0 : O1;

  __shared__ float Xs[32][68];
  __shared__ float Ws[32][68];

  int t = threadIdx.x;
  int tr = t >> 4, tc = t & 15;
  int m0 = blockIdx.x * 64, c0 = blockIdx.y * 64;

  float acc[4][4] = {};

  for (int k0 = 0; k0 < C_; k0 += 32) {
    #pragma unroll
    for (int j2 = 0; j2 < 2; ++j2) {
      int fid = t + j2 * 256;
      int row = fid >> 3;
      int dk  = (fid & 7) << 2;
      float4 xv = *(const float4*)(X + (size_t)(m0 + row) * C_ + k0 + dk);
      Xs[dk+0][row] = xv.x; Xs[dk+1][row] = xv.y; Xs[dk+2][row] = xv.z; Xs[dk+3][row] = xv.w;
      float4 wv = *(const float4*)(W + (size_t)(c0 + row) * C_ + k0 + dk);
      Ws[dk+0][row] = wv.x; Ws[dk+1][row] = wv.y; Ws[dk+2][row] = wv.z; Ws[dk+3][row] = wv.w;
    }
    __syncthreads();
    #pragma unroll
    for (int k = 0; k < 32; ++k) {
      float4 a = *(const float4*)&Xs[k][tr << 2];
      float4 b = *(const float4*)&Ws[k][tc << 2];
      float ar[4] = {a.x, a.y, a.z, a.w};
      float br[4] = {b.x, b.y, b.z, b.w};
      #pragma unroll
      for (int i = 0; i < 4; ++i)
        #pragma unroll
        for (int j = 0; j < 4; ++j)
          acc[i][j] = fmaf(ar[i], br[j], acc[i][j]);
    }
    __syncthreads();
  }

  float bv[4];
  #pragma unroll
  for (int j = 0; j < 4; ++j) bv[j] = bs[c0 + (tc << 2) + j];

  #pragma unroll
  for (int i = 0; i < 4; ++i) {
    float4 o = make_float4(acc[i][0] + bv[0], acc[i][1] + bv[1],
                           acc[i][2] + bv[2], acc[i][3] + bv[3]);
    int m = m0 + (tr << 2) + i;
    int bb = m >> 11;
    int tok = m & (N_ - 1);
    int h = blockIdx.y;
    *(float4*)(O + (((size_t)(bb * H_ + h) * N_) + tok) * D_ + (tc << 2)) = o;
  }
}

// ---- bf16x3 6-pass MFMA GEMM (vh & final proj; post-select paths) ----
__global__ __launch_bounds__(256)
void gemm_mfma(const float* __restrict__ A,
               const unsigned short* __restrict__ Wplanes,
               const float* __restrict__ bias,
               float* __restrict__ O, int scatter)
{
  const size_t WN = (size_t)C_ * C_;
  const unsigned short* Wh = Wplanes;
  const unsigned short* Wm = Wplanes + WN;
  const unsigned short* Wl = Wplanes + 2 * WN;

  __shared__ unsigned short Ah[128][32], Am[128][32], Al[128][32];
  __shared__ unsigned short Bh[64][32],  Bm[64][32],  Bl[64][32];

  int t = threadIdx.x;
  int l = t & 63, wv = t >> 6;
  int wm = wv >> 1, wn = wv & 1;
  int m0 = blockIdx.x * 128, n0 = blockIdx.y * 64;

  f32x4 acc[4][2];
  #pragma unroll
  for (int i = 0; i < 4; ++i)
    #pragma unroll
    for (int j = 0; j < 2; ++j) acc[i][j] = (f32x4){0.f,0.f,0.f,0.f};

  for (int k0 = 0; k0 < C_; k0 += 32) {
    #pragma unroll
    for (int sj = 0; sj < 2; ++sj) {
      int s = t + sj * 256;
      int r = s >> 2, sl = s & 3, c = sl << 3;
      int co = SWZ(r, sl);
      const float* src = A + (size_t)(m0 + r) * C_ + k0 + c;
      float4 x0 = *(const float4*)src;
      float4 x1 = *(const float4*)(src + 4);
      float xs[8] = {x0.x,x0.y,x0.z,x0.w,x1.x,x1.y,x1.z,x1.w};
      unsigned short hv[8], mv[8], lv[8];
      #pragma unroll
      for (int j = 0; j < 8; ++j) split3(xs[j], hv[j], mv[j], lv[j]);
      *(s16x8*)&Ah[r][co] = *(s16x8*)hv;
      *(s16x8*)&Am[r][co] = *(s16x8*)mv;
      *(s16x8*)&Al[r][co] = *(s16x8*)lv;
    }
    {
      int r = t >> 2, sl = t & 3, c = sl << 3;
      int co = SWZ(r, sl);
      size_t boff = (size_t)(n0 + r) * C_ + k0 + c;
      *(s16x8*)&Bh[r][co] = *(const s16x8*)&Wh[boff];
      *(s16x8*)&Bm[r][co] = *(const s16x8*)&Wm[boff];
      *(s16x8*)&Bl[r][co] = *(const s16x8*)&Wl[boff];
    }
    __syncthreads();

    int lr = l & 15, s0 = l >> 4;
    s16x8 ah[4], am[4], al[4];
    #pragma unroll
    for (int mi = 0; mi < 4; ++mi) {
      int R = wm*64 + mi*16 + lr;
      int co = SWZ(R, s0);
      ah[mi] = *(const s16x8*)&Ah[R][co];
      am[mi] = *(const s16x8*)&Am[R][co];
      al[mi] = *(const s16x8*)&Al[R][co];
    }
    #pragma unroll
    for (int nj = 0; nj < 2; ++nj) {
      int Rb = wn*32 + nj*16 + lr;
      int co = SWZ(Rb, s0);
      s16x8 bh = *(const s16x8*)&Bh[Rb][co];
      s16x8 bm = *(const s16x8*)&Bm[Rb][co];
      s16x8 bl = *(const s16x8*)&Bl[Rb][co];
      #pragma unroll
      for (int mi = 0; mi < 4; ++mi)
        SIX_PASS(acc[mi][nj], ah[mi], am[mi], al[mi], bh, bm, bl);
    }
    __syncthreads();
  }

  int lr = l & 15, lq = l >> 4;
  #pragma unroll
  for (int mi = 0; mi < 4; ++mi) {
    #pragma unroll
    for (int nj = 0; nj < 2; ++nj) {
      #pragma unroll
      for (int r = 0; r < 4; ++r) {
        int m = m0 + wm*64 + mi*16 + lq*4 + r;
        int c = n0 + wn*32 + nj*16 + lr;
        float y = acc[mi][nj][r] + bias[c];
        if (scatter) {
          int bb = m >> 11, tok = m & (N_ - 1);
          int hh = c >> 6, d = c & 63;
          O[(((size_t)(bb * H_ + hh) * N_) + tok) * D_ + d] = y;
        } else {
          O[(size_t)m * C_ + c] = y;
        }
      }
    }
  }
}

// ---- EXACT f32 QK^T: 128x128 tile, 8x8 micro (r7/r11-r15 proven) ----
__global__ __launch_bounds__(256)
void qk128(const float* __restrict__ qh, const float* __restrict__ kh,
           float* __restrict__ S, int slice0, int row0, int Rrows)
{
  int z = blockIdx.z;
  int slice = slice0 + z;
  const float* Q = qh + (size_t)slice * N_ * D_;
  const float* K = kh + (size_t)slice * N_ * D_;
  float* Sp = S + (size_t)z * Rrows * N_;

  __shared__ float Qs[32][132];
  __shared__ float Ks[32][132];

  int t = threadIdx.x;
  int tr = t >> 4, tc = t & 15;
  int n0 = blockIdx.x * 128, m0 = blockIdx.y * 128;

  float acc[2][2][4][4] = {};

  #pragma unroll
  for (int k0 = 0; k0 < D_; k0 += 32) {
    #pragma unroll
    for (int jj = 0; jj < 4; ++jj) {
      int fid = t + jj * 256;
      int row = fid >> 3;
      int dk  = (fid & 7) << 2;
      float4 qv = *(const float4*)(Q + (size_t)(row0 + n0 + row) * D_ + k0 + dk);
      Qs[dk+0][row] = qv.x; Qs[dk+1][row] = qv.y; Qs[dk+2][row] = qv.z; Qs[dk+3][row] = qv.w;
      float4 kv = *(const float4*)(K + (size_t)(m0 + row) * D_ + k0 + dk);
      Ks[dk+0][row] = kv.x; Ks[dk+1][row] = kv.y; Ks[dk+2][row] = kv.z; Ks[dk+3][row] = kv.w;
    }
    __syncthreads();
    #pragma unroll 8
    for (int k = 0; k < 32; ++k) {
      float a[2][4], b[2][4];
      *(float4*)&a[0][0] = *(const float4*)&Qs[k][tr << 2];
      *(float4*)&a[1][0] = *(const float4*)&Qs[k][64 + (tr << 2)];
      *(float4*)&b[0][0] = *(const float4*)&Ks[k][tc << 2];
      *(float4*)&b[1][0] = *(const float4*)&Ks[k][64 + (tc << 2)];
      #pragma unroll
      for (int ia = 0; ia < 2; ++ia)
        #pragma unroll
        for (int ib = 0; ib < 2; ++ib)
          #pragma unroll
          for (int i = 0; i < 4; ++i)
            #pragma unroll
            for (int j = 0; j < 4; ++j)
              acc[ia][ib][i][j] = fmaf(a[ia][i], b[ib][j], acc[ia][ib][i][j]);
    }
    __syncthreads();
  }

  const float scale = 0.125f;
  #pragma unroll
  for (int ia = 0; ia < 2; ++ia)
    #pragma unroll
    for (int i = 0; i < 4; ++i) {
      int n = n0 + ia*64 + (tr << 2) + i;
      #pragma unroll
      for (int ib = 0; ib < 2; ++ib) {
        float4 o = make_float4(acc[ia][ib][i][0] * scale, acc[ia][ib][i][1] * scale,
                               acc[ia][ib][i][2] * scale, acc[ia][ib][i][3] * scale);
        *(float4*)(Sp + (size_t)n * N_ + m0 + ib*64 + (tc << 2)) = o;
      }
    }
}

// ---- one wave per row: two-stage exact radix-select, register-cached list ----
// Phase A: full scans until a taken bit's count lands in (TOPK, CAP].
// Compaction: per-lane count + wave prefix-scan + sequential writes (list
// order is lane-major now — only the PV summation ORDER changes, which is
// post-select and numerically ~1 ulp; the kept SET is provably identical).
// Phase B: candidates cached in 4 regs/lane; ballot+popcll counting (SALU).
__global__ __launch_bounds__(256)
void topk_softmax_pv(const float* __restrict__ S, const float* __restrict__ vh,
                     float* __restrict__ outp, int slice0, int row0, int log2R)
{
  __shared__ float wL[4][CAP_];          // u32 candidate vals, then f32 weights
  __shared__ unsigned short iL[4][CAP_]; // col indices

  int t = threadIdx.x;
  int wv = t >> 6;
  int lane = t & 63;
  int gr = blockIdx.x * 4 + wv;
  int s_local = gr >> log2R;
  int rrow = gr & ((1 << log2R) - 1);
  int slice = slice0 + s_local;
  int row = row0 + rrow;

  const float* Srow = S + ((size_t)gr) * N_;

  unsigned u[32];
  #pragma unroll
  for (int i = 0; i < 8; ++i) {
    float4 v = *(const float4*)(Srow + i * 256 + lane * 4);
    float xv[4] = {v.x, v.y, v.z, v.w};
    #pragma unroll
    for (int c = 0; c < 4; ++c) {
      unsigned bits = __float_as_uint(xv[c]);
      u[i*4+c] = bits ^ ((unsigned)(((int)bits) >> 31) | 0x80000000u);
    }
  }

  unsigned mxu = 0u;
  #pragma unroll
  for (int i = 0; i < 32; ++i) mxu = (u[i] > mxu) ? u[i] : mxu;
  #pragma unroll
  for (int off = 32; off >= 1; off >>= 1) {
    unsigned o = (unsigned)__shfl_xor((int)mxu, off);
    mxu = (o > mxu) ? o : mxu;
  }
  unsigned mxs = (unsigned)__builtin_amdgcn_readfirstlane((int)mxu);
  float mx = u2f(mxs);

  unsigned* uList = (unsigned*)&wL[wv][0];
  const float* Vs = vh + (size_t)slice * N_ * D_;

  // ---- Phase A: full scans until success count lands in (TOPK, CAP] ----
  unsigned thr = 0u;
  int cnt = -1;
  int kc = 0;            // per-lane kept count at final Phase-A thr
  for (int bit = 31; bit >= 0; --bit) {
    unsigned cand = thr | (1u << bit);
    if (cand > mxs) continue;
    int c = 0;
    #pragma unroll
    for (int i = 0; i < 32; ++i) c += (u[i] >= cand) ? 1 : 0;
    int cl = c;          // per-lane count before reduce
    #pragma unroll
    for (int off = 32; off >= 1; off >>= 1) c += __shfl_xor(c, off);
    if (c >= TOPK_) {
      thr = cand;
      if (c == TOPK_) break;
      if (c <= CAP_) { cnt = c; kc = cl; break; }
    }
  }

  float s = 0.f;
  int total = 0;

  if (cnt >= 0) {
    // prefix-sum compaction: exclusive scan of per-lane kept counts
    int incl = kc;
    #pragma unroll
    for (int off = 1; off < 64; off <<= 1) {
      int vv = __shfl_up(incl, off);
      if ((int)lane >= off) incl += vv;
    }
    int p = incl - kc;   // exclusive prefix = my write base
    #pragma unroll
    for (int i = 0; i < 32; ++i) {
      if (u[i] >= thr) {
        uList[p] = u[i];
        iL[wv][p] = (unsigned short)(((i >> 2) << 8) + (lane << 2) + (i & 3));
        ++p;
      }
    }
    // read the list back into registers (4 candidates per lane)
    unsigned cu[4];
    unsigned short ci[4];
    #pragma unroll
    for (int j = 0; j < 4; ++j) {
      int e = lane + (j << 6);
      bool valid = (e < cnt);
      cu[j] = valid ? uList[e] : 0u;
      ci[j] = valid ? iL[wv][e] : (unsigned short)0;
    }
    // ---- Phase B: refine over register list; ballot/popcll counting ----
    // (cand >= 1 always, invalid slots are 0 -> never counted)
    for (int bit = 31; bit >= 0; --bit) {
      unsigned cand = thr | (1u << bit);
      if (cand <= thr || cand > mxs) continue;   // bit already in thr or dead
      int c = __popcll(__ballot(cu[0] >= cand))
            + __popcll(__ballot(cu[1] >= cand))
            + __popcll(__ballot(cu[2] >= cand))
            + __popcll(__ballot(cu[3] >= cand));
      if (c >= TOPK_) {
        thr = cand;
        if (c == TOPK_) break;
      }
    }
    // ---- extraction from register list (4 ballot steps, list order) ----
    int base2 = 0;
    #pragma unroll
    for (int j = 0; j < 4; ++j) {
      int e = lane + (j << 6);
      bool kp = (e < cnt) && (cu[j] >= thr);
      float ev = kp ? __expf(u2f(cu[j]) - mx) : 0.f;
      s += ev;
      unsigned long long m = __ballot(kp);
      if (kp) {
        int pos = base2 + mbcnt64(m);
        wL[wv][pos] = ev;
        iL[wv][pos] = ci[j];
      }
      base2 += __popcll(m);
    }
    total = base2;
  } else {
    // fallback (early c==TOPK exit or tie-heavy rows): register path (r13)
    int base = 0;
    #pragma unroll
    for (int i = 0; i < 32; ++i) {
      bool kp = (u[i] >= thr);
      unsigned long long m = __ballot(kp);
      float ev = kp ? __expf(u2f(u[i]) - mx) : 0.f;
      s += ev;
      if (kp) {
        int pos = base + mbcnt64(m);
        if (pos < CAP_) {
          wL[wv][pos] = ev;
          iL[wv][pos] = (unsigned short)(((i >> 2) << 8) + (lane << 2) + (i & 3));
        }
      }
      base += __popcll(m);
    }
    total = base < CAP_ ? base : CAP_;
  }

  #pragma unroll
  for (int off = 32; off >= 1; off >>= 1) s += __shfl_xor(s, off);
  float inv = 1.f / s;

  // gather-PV, 8-deep ILP, vectorized list reads; normalize once at end
  float a0=0.f,a1=0.f,a2=0.f,a3=0.f,a4=0.f,a5=0.f,a6=0.f,a7=0.f;
  int e = 0;
  for (; e + 8 <= total; e += 8) {
    float4 wa = *(const float4*)&wL[wv][e];
    float4 wb = *(const float4*)&wL[wv][e+4];
    u16x8 jj = *(const u16x8*)&iL[wv][e];
    float v0=Vs[(size_t)jj[0]*D_+lane], v1=Vs[(size_t)jj[1]*D_+lane];
    float v2=Vs[(size_t)jj[2]*D_+lane], v3=Vs[(size_t)jj[3]*D_+lane];
    float v4=Vs[(size_t)jj[4]*D_+lane], v5=Vs[(size_t)jj[5]*D_+lane];
    float v6=Vs[(size_t)jj[6]*D_+lane], v7=Vs[(size_t)jj[7]*D_+lane];
    a0 = fmaf(wa.x, v0, a0); a1 = fmaf(wa.y, v1, a1);
    a2 = fmaf(wa.z, v2, a2); a3 = fmaf(wa.w, v3, a3);
    a4 = fmaf(wb.x, v4, a4); a5 = fmaf(wb.y, v5, a5);
    a6 = fmaf(wb.z, v6, a6); a7 = fmaf(wb.w, v7, a7);
  }
  for (; e < total; ++e)
    a0 = fmaf(wL[wv][e], Vs[(size_t)iL[wv][e] * D_ + lane], a0);
  float acc = (((a0 + a1) + (a2 + a3)) + ((a4 + a5) + (a6 + a7))) * inv;

  int b = slice >> 3;
  int h = slice & 7;
  outp[((size_t)(b * N_ + row)) * C_ + h * D_ + lane] = acc;
}

extern "C" void kernel_launch(void* const* d_in, const int* in_sizes, int n_in,
                              void* d_out, int out_size, void* d_ws, size_t ws_size,
                              hipStream_t stream) {
  const float* q  = (const float*)d_in[0];
  const float* k  = (const float*)d_in[1];
  const float* v  = (const float*)d_in[2];
  const float* Wq = (const float*)d_in[3];
  const float* bq = (const float*)d_in[4];
  const float* Wk = (const float*)d_in[5];
  const float* bk = (const float*)d_in[6];
  const float* Wv = (const float*)d_in[7];
  const float* bv = (const float*)d_in[8];
  const float* Wp = (const float*)d_in[9];
  const float* bp = (const float*)d_in[10];

  const size_t NB = (size_t)B_ * H_ * N_ * D_;   // 2,097,152 floats
  const size_t WN = (size_t)C_ * C_;
  float* qh  = (float*)d_ws;
  float* kh  = qh + NB;
  float* vh  = kh + NB;
  float* pre = vh + NB;
  unsigned short* Wsp = (unsigned short*)(pre + NB);   // 2 x 3 x WN u16
  float* S   = (float*)(Wsp + 2 * 3 * WN);

  size_t fixedB = 4 * NB * 4 + 2 * 3 * WN * 2;         // ~35.1 MB
  size_t sliceB = (size_t)N_ * N_ * 4;                 // 16.78 MB
  size_t avail = (ws_size > fixedB) ? ws_size - fixedB : 0;

  // ns=16 (r14 config): FETCH at ns=8 was unchanged (L3 absorbs either way);
  // fewer launch boundaries wins (r14 361.0 vs r15 364.8).
  int ns = 1, R = 2048;
  if      (avail >= 16 * sliceB) { ns = 16; R = 2048; }
  else if (avail >= 8 * sliceB)  { ns = 8;  R = 2048; }
  else if (avail >= 4 * sliceB)  { ns = 4;  R = 2048; }
  else if (avail >= 2 * sliceB)  { ns = 2;  R = 2048; }
  else if (avail >= 1 * sliceB)  { ns = 1;  R = 2048; }
  else if (avail >= sliceB / 2)  { ns = 1;  R = 1024; }
  else                           { ns = 1;  R = 512;  }
  int log2R = (R == 2048) ? 11 : ((R == 1024) ? 10 : 9);

  dim3 blk(256);

  // weight splits for the two MFMA GEMMs (Wv, Wp)
  wsplit<<<dim3(WN / 256, 2), blk, 0, stream>>>(Wv, Wp, Wsp);

  // q,k projections: EXACT f32 chain, head-scatter
  gemm64<<<dim3(BN_/64, C_/64, 2), blk, 0, stream>>>(
      q, k, Wq, Wk, bq, bk, qh, kh);

  // v projection: bf16x3 6-pass MFMA (post-select path), head-scatter
  gemm_mfma<<<dim3(BN_/128, C_/64), blk, 0, stream>>>(
      v, Wsp, bv, vh, 1);

  for (int s0 = 0; s0 < B_ * H_; s0 += ns) {
    int cur = (B_ * H_ - s0) < ns ? (B_ * H_ - s0) : ns;
    for (int r0 = 0; r0 < N_; r0 += R) {
      qk128<<<dim3(R/128, N_/128, cur), blk, 0, stream>>>(qh, kh, S, s0, r0, R);
      topk_softmax_pv<<<dim3(cur * (R/4)), blk, 0, stream>>>(S, vh, pre, s0, r0, log2R);
    }
  }

  // final projection: bf16x3 6-pass MFMA -> d_out
  gemm_mfma<<<dim3(BN_/128, C_/64), blk, 0, stream>>>(
      pre, Wsp + 3 * WN, bp, (float*)d_out, 0);
}

// Round 17
// 339.508 us; speedup vs baseline: 1.0746x; 1.0089x over previous
//
#include <hip/hip_runtime.h>
#include <stdint.h>

#define B_ 2
#define N_ 2048
#define C_ 512
#define H_ 8
#define D_ 64
#define TOPK_ 100
#define BN_ (B_*N_)
#define CAP_ 256

typedef __attribute__((ext_vector_type(8))) short s16x8;
typedef __attribute__((ext_vector_type(8))) unsigned short u16x8;
typedef __attribute__((ext_vector_type(4))) float f32x4;

__device__ __forceinline__ int mbcnt64(unsigned long long m) {
  return __builtin_amdgcn_mbcnt_hi((unsigned)(m >> 32),
         __builtin_amdgcn_mbcnt_lo((unsigned)m, 0u));
}
// order-preserving f32 <-> u32 bijection (exact roundtrip; r10-r16 proven)
__device__ __forceinline__ float u2f(unsigned uu) {
  unsigned bits = (uu & 0x80000000u) ? (uu ^ 0x80000000u) : ~uu;
  return __uint_as_float(bits);
}
__device__ __forceinline__ unsigned short bf16rn(float x) {
  unsigned u = __float_as_uint(x);
  unsigned r = (u + 0x7fffu + ((u >> 16) & 1u)) >> 16;
  return (unsigned short)r;
}
__device__ __forceinline__ float bf16f(unsigned short h) {
  return __uint_as_float(((unsigned)h) << 16);
}
__device__ __forceinline__ void split3(float x, unsigned short& h,
                                       unsigned short& m, unsigned short& l) {
  h = bf16rn(x);
  float r1 = x - bf16f(h);
  m = bf16rn(r1);
  float r2 = r1 - bf16f(m);
  l = bf16rn(r2);
}
#define SWZ(r, sl) (((sl) ^ (((r) >> 1) & 3)) << 3)
#define MFMA_BF16(a, b, c) __builtin_amdgcn_mfma_f32_16x16x32_bf16(a, b, c, 0, 0, 0)
#define SIX_PASS(acc, ah, am, al, bh, bm, bl) \
  do { \
    acc = MFMA_BF16(ah, bl, acc); \
    acc = MFMA_BF16(am, bm, acc); \
    acc = MFMA_BF16(al, bh, acc); \
    acc = MFMA_BF16(ah, bm, acc); \
    acc = MFMA_BF16(am, bh, acc); \
    acc = MFMA_BF16(ah, bh, acc); \
  } while (0)

// ==== bf16x3 6-pass MFMA GEMM body (post-select paths: vh, final proj) ====
// W split on the fly (same split3 values as the old wsplit -> bit-identical).
__device__ __forceinline__ void mfma_body(
    const float* __restrict__ A, const float* __restrict__ Wraw,
    const float* __restrict__ bias, float* __restrict__ O, int scatter,
    int m0, int n0, char* smem, int t)
{
  auto Ah = (unsigned short (*)[32])(smem);            // [128][32]
  auto Am = (unsigned short (*)[32])(smem + 8192);
  auto Al = (unsigned short (*)[32])(smem + 16384);
  auto Bh = (unsigned short (*)[32])(smem + 24576);    // [64][32]
  auto Bm = (unsigned short (*)[32])(smem + 28672);
  auto Bl = (unsigned short (*)[32])(smem + 32768);

  int l = t & 63, wv = t >> 6;
  int wm = wv >> 1, wn = wv & 1;

  f32x4 acc[4][2];
  #pragma unroll
  for (int i = 0; i < 4; ++i)
    #pragma unroll
    for (int j = 0; j < 2; ++j) acc[i][j] = (f32x4){0.f,0.f,0.f,0.f};

  for (int k0 = 0; k0 < C_; k0 += 32) {
    #pragma unroll
    for (int sj = 0; sj < 2; ++sj) {
      int s = t + sj * 256;
      int r = s >> 2, sl = s & 3, c = sl << 3;
      int co = SWZ(r, sl);
      const float* src = A + (size_t)(m0 + r) * C_ + k0 + c;
      float4 x0 = *(const float4*)src;
      float4 x1 = *(const float4*)(src + 4);
      float xs[8] = {x0.x,x0.y,x0.z,x0.w,x1.x,x1.y,x1.z,x1.w};
      unsigned short hv[8], mv[8], lv[8];
      #pragma unroll
      for (int j = 0; j < 8; ++j) split3(xs[j], hv[j], mv[j], lv[j]);
      *(s16x8*)&Ah[r][co] = *(s16x8*)hv;
      *(s16x8*)&Am[r][co] = *(s16x8*)mv;
      *(s16x8*)&Al[r][co] = *(s16x8*)lv;
    }
    {
      int r = t >> 2, sl = t & 3, c = sl << 3;
      int co = SWZ(r, sl);
      const float* src = Wraw + (size_t)(n0 + r) * C_ + k0 + c;
      float4 x0 = *(const float4*)src;
      float4 x1 = *(const float4*)(src + 4);
      float xs[8] = {x0.x,x0.y,x0.z,x0.w,x1.x,x1.y,x1.z,x1.w};
      unsigned short hv[8], mv[8], lv[8];
      #pragma unroll
      for (int j = 0; j < 8; ++j) split3(xs[j], hv[j], mv[j], lv[j]);
      *(s16x8*)&Bh[r][co] = *(s16x8*)hv;
      *(s16x8*)&Bm[r][co] = *(s16x8*)mv;
      *(s16x8*)&Bl[r][co] = *(s16x8*)lv;
    }
    __syncthreads();

    int lr = l & 15, s0 = l >> 4;
    s16x8 ah[4], am[4], al[4];
    #pragma unroll
    for (int mi = 0; mi < 4; ++mi) {
      int R = wm*64 + mi*16 + lr;
      int co = SWZ(R, s0);
      ah[mi] = *(const s16x8*)&Ah[R][co];
      am[mi] = *(const s16x8*)&Am[R][co];
      al[mi] = *(const s16x8*)&Al[R][co];
    }
    #pragma unroll
    for (int nj = 0; nj < 2; ++nj) {
      int Rb = wn*32 + nj*16 + lr;
      int co = SWZ(Rb, s0);
      s16x8 bh = *(const s16x8*)&Bh[Rb][co];
      s16x8 bm = *(const s16x8*)&Bm[Rb][co];
      s16x8 bl = *(const s16x8*)&Bl[Rb][co];
      #pragma unroll
      for (int mi = 0; mi < 4; ++mi)
        SIX_PASS(acc[mi][nj], ah[mi], am[mi], al[mi], bh, bm, bl);
    }
    __syncthreads();
  }

  int lr = l & 15, lq = l >> 4;
  #pragma unroll
  for (int mi = 0; mi < 4; ++mi) {
    #pragma unroll
    for (int nj = 0; nj < 2; ++nj) {
      #pragma unroll
      for (int r = 0; r < 4; ++r) {
        int m = m0 + wm*64 + mi*16 + lq*4 + r;
        int c = n0 + wn*32 + nj*16 + lr;
        float y = acc[mi][nj][r] + bias[c];
        if (scatter) {
          int bb = m >> 11, tok = m & (N_ - 1);
          int hh = c >> 6, d = c & 63;
          O[(((size_t)(bb * H_ + hh) * N_) + tok) * D_ + d] = y;
        } else {
          O[(size_t)m * C_ + c] = y;
        }
      }
    }
  }
}

// ==== EXACT f32 64x64 GEMM body for qh/kh (r7-proven structure) ====
// NUMERICS CONTRACT: per output, strictly k-ascending single-acc fmaf chain
// (k=0..511), bias added once at the end — bit-identical to r6-r16.
// NEW (perf only): staging-write swizzle col = row ^ ((dk>>2 & 3)<<3) —
// write banks 4-way -> 2-way (free); float4 reads stay contiguous (bits 3-4).
__device__ __forceinline__ void gemm64_body(
    const float* __restrict__ X, const float* __restrict__ W,
    const float* __restrict__ bs, float* __restrict__ O,
    int m0, int c0, int hsel, char* smem, int t)
{
  auto Xs = (float (*)[68])(smem);           // [32][68]
  auto Ws = (float (*)[68])(smem + 8704);    // [32][68]

  int tr = t >> 4, tc = t & 15;

  float acc[4][4] = {};

  for (int k0 = 0; k0 < C_; k0 += 32) {
    #pragma unroll
    for (int j2 = 0; j2 < 2; ++j2) {
      int fid = t + j2 * 256;
      int row = fid >> 3;
      int dk  = (fid & 7) << 2;
      int f   = ((dk >> 2) & 3) << 3;
      int co  = row ^ f;
      float4 xv = *(const float4*)(X + (size_t)(m0 + row) * C_ + k0 + dk);
      Xs[dk+0][co] = xv.x; Xs[dk+1][co] = xv.y; Xs[dk+2][co] = xv.z; Xs[dk+3][co] = xv.w;
      float4 wv = *(const float4*)(W + (size_t)(c0 + row) * C_ + k0 + dk);
      Ws[dk+0][co] = wv.x; Ws[dk+1][co] = wv.y; Ws[dk+2][co] = wv.z; Ws[dk+3][co] = wv.w;
    }
    __syncthreads();
    #pragma unroll
    for (int k = 0; k < 32; ++k) {
      int fk = ((k >> 2) & 3) << 3;
      float4 a = *(const float4*)&Xs[k][(tr << 2) ^ fk];
      float4 b = *(const float4*)&Ws[k][(tc << 2) ^ fk];
      float ar[4] = {a.x, a.y, a.z, a.w};
      float br[4] = {b.x, b.y, b.z, b.w};
      #pragma unroll
      for (int i = 0; i < 4; ++i)
        #pragma unroll
        for (int j = 0; j < 4; ++j)
          acc[i][j] = fmaf(ar[i], br[j], acc[i][j]);
    }
    __syncthreads();
  }

  float bv[4];
  #pragma unroll
  for (int j = 0; j < 4; ++j) bv[j] = bs[c0 + (tc << 2) + j];

  #pragma unroll
  for (int i = 0; i < 4; ++i) {
    float4 o = make_float4(acc[i][0] + bv[0], acc[i][1] + bv[1],
                           acc[i][2] + bv[2], acc[i][3] + bv[3]);
    int m = m0 + (tr << 2) + i;
    int bb = m >> 11;
    int tok = m & (N_ - 1);
    *(float4*)(O + (((size_t)(bb * H_ + hsel) * N_) + tok) * D_ + (tc << 2)) = o;
  }
}

// ==== merged front kernel: blocks 0..255 = v-projection (MFMA, long blocks
// first), 256..1279 = q,k projections (exact f32 chain) ====
__global__ __launch_bounds__(256)
void proj_all(const float* __restrict__ q, const float* __restrict__ k,
              const float* __restrict__ v,
              const float* __restrict__ Wq, const float* __restrict__ Wk,
              const float* __restrict__ Wv,
              const float* __restrict__ bq, const float* __restrict__ bk,
              const float* __restrict__ bv,
              float* __restrict__ qh, float* __restrict__ kh,
              float* __restrict__ vh)
{
  __shared__ __align__(16) char smem[36864];
  int t = threadIdx.x;
  int id = blockIdx.x;
  if (id < 256) {
    int m0 = (id & 31) * 128, n0 = (id >> 5) * 64;
    mfma_body(v, Wv, bv, vh, 1, m0, n0, smem, t);
  } else {
    int g = id - 256;
    int z = g >> 9;
    int m0 = (g & 63) * 64;
    int hy = (g >> 6) & 7;
    gemm64_body(z ? k : q, z ? Wk : Wq, z ? bk : bq, z ? kh : qh,
                m0, hy * 64, hy, smem, t);
  }
}

// ==== final projection: bf16x3 MFMA, W split on the fly ====
__global__ __launch_bounds__(256)
void gemm_mfma_final(const float* __restrict__ pre, const float* __restrict__ Wp,
                     const float* __restrict__ bp, float* __restrict__ O)
{
  __shared__ __align__(16) char smem[36864];
  mfma_body(pre, Wp, bp, O, 0, blockIdx.x * 128, blockIdx.y * 64,
            smem, threadIdx.x);
}

// ==== EXACT f32 QK^T: 128x128 tile, 8x8 micro (r7/r11-r16 proven chain) ====
// NEW (perf only): same staging-write swizzle as gemm64.
__global__ __launch_bounds__(256)
void qk128(const float* __restrict__ qh, const float* __restrict__ kh,
           float* __restrict__ S, int slice0, int row0, int Rrows)
{
  int z = blockIdx.z;
  int slice = slice0 + z;
  const float* Q = qh + (size_t)slice * N_ * D_;
  const float* K = kh + (size_t)slice * N_ * D_;
  float* Sp = S + (size_t)z * Rrows * N_;

  __shared__ float Qs[32][132];
  __shared__ float Ks[32][132];

  int t = threadIdx.x;
  int tr = t >> 4, tc = t & 15;
  int n0 = blockIdx.x * 128, m0 = blockIdx.y * 128;

  float acc[2][2][4][4] = {};

  #pragma unroll
  for (int k0 = 0; k0 < D_; k0 += 32) {
    #pragma unroll
    for (int jj = 0; jj < 4; ++jj) {
      int fid = t + jj * 256;
      int row = fid >> 3;
      int dk  = (fid & 7) << 2;
      int f   = ((dk >> 2) & 3) << 3;
      int co  = row ^ f;
      float4 qv = *(const float4*)(Q + (size_t)(row0 + n0 + row) * D_ + k0 + dk);
      Qs[dk+0][co] = qv.x; Qs[dk+1][co] = qv.y; Qs[dk+2][co] = qv.z; Qs[dk+3][co] = qv.w;
      float4 kv = *(const float4*)(K + (size_t)(m0 + row) * D_ + k0 + dk);
      Ks[dk+0][co] = kv.x; Ks[dk+1][co] = kv.y; Ks[dk+2][co] = kv.z; Ks[dk+3][co] = kv.w;
    }
    __syncthreads();
    #pragma unroll 8
    for (int k = 0; k < 32; ++k) {
      int fk = ((k >> 2) & 3) << 3;
      float a[2][4], b[2][4];
      *(float4*)&a[0][0] = *(const float4*)&Qs[k][(tr << 2) ^ fk];
      *(float4*)&a[1][0] = *(const float4*)&Qs[k][(64 + (tr << 2)) ^ fk];
      *(float4*)&b[0][0] = *(const float4*)&Ks[k][(tc << 2) ^ fk];
      *(float4*)&b[1][0] = *(const float4*)&Ks[k][(64 + (tc << 2)) ^ fk];
      #pragma unroll
      for (int ia = 0; ia < 2; ++ia)
        #pragma unroll
        for (int ib = 0; ib < 2; ++ib)
          #pragma unroll
          for (int i = 0; i < 4; ++i)
            #pragma unroll
            for (int j = 0; j < 4; ++j)
              acc[ia][ib][i][j] = fmaf(a[ia][i], b[ib][j], acc[ia][ib][i][j]);
    }
    __syncthreads();
  }

  const float scale = 0.125f;
  #pragma unroll
  for (int ia = 0; ia < 2; ++ia)
    #pragma unroll
    for (int i = 0; i < 4; ++i) {
      int n = n0 + ia*64 + (tr << 2) + i;
      #pragma unroll
      for (int ib = 0; ib < 2; ++ib) {
        float4 o = make_float4(acc[ia][ib][i][0] * scale, acc[ia][ib][i][1] * scale,
                               acc[ia][ib][i][2] * scale, acc[ia][ib][i][3] * scale);
        *(float4*)(Sp + (size_t)n * N_ + m0 + ib*64 + (tc << 2)) = o;
      }
    }
}

// ---- one wave per row: two-stage exact radix-select, register-cached list
// (r16-proven) ----
__global__ __launch_bounds__(256)
void topk_softmax_pv(const float* __restrict__ S, const float* __restrict__ vh,
                     float* __restrict__ outp, int slice0, int row0, int log2R)
{
  __shared__ float wL[4][CAP_];
  __shared__ unsigned short iL[4][CAP_];

  int t = threadIdx.x;
  int wv = t >> 6;
  int lane = t & 63;
  int gr = blockIdx.x * 4 + wv;
  int s_local = gr >> log2R;
  int rrow = gr & ((1 << log2R) - 1);
  int slice = slice0 + s_local;
  int row = row0 + rrow;

  const float* Srow = S + ((size_t)gr) * N_;

  unsigned u[32];
  #pragma unroll
  for (int i = 0; i < 8; ++i) {
    float4 v = *(const float4*)(Srow + i * 256 + lane * 4);
    float xv[4] = {v.x, v.y, v.z, v.w};
    #pragma unroll
    for (int c = 0; c < 4; ++c) {
      unsigned bits = __float_as_uint(xv[c]);
      u[i*4+c] = bits ^ ((unsigned)(((int)bits) >> 31) | 0x80000000u);
    }
  }

  unsigned mxu = 0u;
  #pragma unroll
  for (int i = 0; i < 32; ++i) mxu = (u[i] > mxu) ? u[i] : mxu;
  #pragma unroll
  for (int off = 32; off >= 1; off >>= 1) {
    unsigned o = (unsigned)__shfl_xor((int)mxu, off);
    mxu = (o > mxu) ? o : mxu;
  }
  unsigned mxs = (unsigned)__builtin_amdgcn_readfirstlane((int)mxu);
  float mx = u2f(mxs);

  unsigned* uList = (unsigned*)&wL[wv][0];
  const float* Vs = vh + (size_t)slice * N_ * D_;

  // ---- Phase A: full scans until success count lands in (TOPK, CAP] ----
  unsigned thr = 0u;
  int cnt = -1;
  int kc = 0;
  for (int bit = 31; bit >= 0; --bit) {
    unsigned cand = thr | (1u << bit);
    if (cand > mxs) continue;
    int c = 0;
    #pragma unroll
    for (int i = 0; i < 32; ++i) c += (u[i] >= cand) ? 1 : 0;
    int cl = c;
    #pragma unroll
    for (int off = 32; off >= 1; off >>= 1) c += __shfl_xor(c, off);
    if (c >= TOPK_) {
      thr = cand;
      if (c == TOPK_) break;
      if (c <= CAP_) { cnt = c; kc = cl; break; }
    }
  }

  float s = 0.f;
  int total = 0;

  if (cnt >= 0) {
    // prefix-sum compaction
    int incl = kc;
    #pragma unroll
    for (int off = 1; off < 64; off <<= 1) {
      int vv = __shfl_up(incl, off);
      if ((int)lane >= off) incl += vv;
    }
    int p = incl - kc;
    #pragma unroll
    for (int i = 0; i < 32; ++i) {
      if (u[i] >= thr) {
        uList[p] = u[i];
        iL[wv][p] = (unsigned short)(((i >> 2) << 8) + (lane << 2) + (i & 3));
        ++p;
      }
    }
    // register-cached list
    unsigned cu[4];
    unsigned short ci[4];
    #pragma unroll
    for (int j = 0; j < 4; ++j) {
      int e = lane + (j << 6);
      bool valid = (e < cnt);
      cu[j] = valid ? uList[e] : 0u;
      ci[j] = valid ? iL[wv][e] : (unsigned short)0;
    }
    // ---- Phase B: refine; ballot/popcll counting ----
    for (int bit = 31; bit >= 0; --bit) {
      unsigned cand = thr | (1u << bit);
      if (cand > mxs) continue;
      if (thr & (1u << bit)) continue;   // bit already taken
      int c = __popcll(__ballot(cu[0] >= cand))
            + __popcll(__ballot(cu[1] >= cand))
            + __popcll(__ballot(cu[2] >= cand))
            + __popcll(__ballot(cu[3] >= cand));
      if (c >= TOPK_) {
        thr = cand;
        if (c == TOPK_) break;
      }
    }
    // ---- extraction from register list ----
    int base2 = 0;
    #pragma unroll
    for (int j = 0; j < 4; ++j) {
      int e = lane + (j << 6);
      bool kp = (e < cnt) && (cu[j] >= thr);
      float ev = kp ? __expf(u2f(cu[j]) - mx) : 0.f;
      s += ev;
      unsigned long long m = __ballot(kp);
      if (kp) {
        int pos = base2 + mbcnt64(m);
        wL[wv][pos] = ev;
        iL[wv][pos] = ci[j];
      }
      base2 += __popcll(m);
    }
    total = base2;
  } else {
    // fallback: register path
    int base = 0;
    #pragma unroll
    for (int i = 0; i < 32; ++i) {
      bool kp = (u[i] >= thr);
      unsigned long long m = __ballot(kp);
      float ev = kp ? __expf(u2f(u[i]) - mx) : 0.f;
      s += ev;
      if (kp) {
        int pos = base + mbcnt64(m);
        if (pos < CAP_) {
          wL[wv][pos] = ev;
          iL[wv][pos] = (unsigned short)(((i >> 2) << 8) + (lane << 2) + (i & 3));
        }
      }
      base += __popcll(m);
    }
    total = base < CAP_ ? base : CAP_;
  }

  #pragma unroll
  for (int off = 32; off >= 1; off >>= 1) s += __shfl_xor(s, off);
  float inv = 1.f / s;

  // gather-PV, 8-deep ILP, vectorized list reads; normalize once at end
  float a0=0.f,a1=0.f,a2=0.f,a3=0.f,a4=0.f,a5=0.f,a6=0.f,a7=0.f;
  int e = 0;
  for (; e + 8 <= total; e += 8) {
    float4 wa = *(const float4*)&wL[wv][e];
    float4 wb = *(const float4*)&wL[wv][e+4];
    u16x8 jj = *(const u16x8*)&iL[wv][e];
    float v0=Vs[(size_t)jj[0]*D_+lane], v1=Vs[(size_t)jj[1]*D_+lane];
    float v2=Vs[(size_t)jj[2]*D_+lane], v3=Vs[(size_t)jj[3]*D_+lane];
    float v4=Vs[(size_t)jj[4]*D_+lane], v5=Vs[(size_t)jj[5]*D_+lane];
    float v6=Vs[(size_t)jj[6]*D_+lane], v7=Vs[(size_t)jj[7]*D_+lane];
    a0 = fmaf(wa.x, v0, a0); a1 = fmaf(wa.y, v1, a1);
    a2 = fmaf(wa.z, v2, a2); a3 = fmaf(wa.w, v3, a3);
    a4 = fmaf(wb.x, v4, a4); a5 = fmaf(wb.y, v5, a5);
    a6 = fmaf(wb.z, v6, a6); a7 = fmaf(wb.w, v7, a7);
  }
  for (; e < total; ++e)
    a0 = fmaf(wL[wv][e], Vs[(size_t)iL[wv][e] * D_ + lane], a0);
  float acc = (((a0 + a1) + (a2 + a3)) + ((a4 + a5) + (a6 + a7))) * inv;

  int b = slice >> 3;
  int h = slice & 7;
  outp[((size_t)(b * N_ + row)) * C_ + h * D_ + lane] = acc;
}

extern "C" void kernel_launch(void* const* d_in, const int* in_sizes, int n_in,
                              void* d_out, int out_size, void* d_ws, size_t ws_size,
                              hipStream_t stream) {
  const float* q  = (const float*)d_in[0];
  const float* k  = (const float*)d_in[1];
  const float* v  = (const float*)d_in[2];
  const float* Wq = (const float*)d_in[3];
  const float* bq = (const float*)d_in[4];
  const float* Wk = (const float*)d_in[5];
  const float* bk = (const float*)d_in[6];
  const float* Wv = (const float*)d_in[7];
  const float* bv = (const float*)d_in[8];
  const float* Wp = (const float*)d_in[9];
  const float* bp = (const float*)d_in[10];

  const size_t NB = (size_t)B_ * H_ * N_ * D_;   // 2,097,152 floats
  float* qh  = (float*)d_ws;
  float* kh  = qh + NB;
  float* vh  = kh + NB;
  float* pre = vh + NB;
  float* S   = pre + NB;

  size_t fixedB = 4 * NB * 4;                          // 33.6 MB
  size_t sliceB = (size_t)N_ * N_ * 4;                 // 16.78 MB
  size_t avail = (ws_size > fixedB) ? ws_size - fixedB : 0;

  int ns = 1, R = 2048;
  if      (avail >= 16 * sliceB) { ns = 16; R = 2048; }
  else if (avail >= 8 * sliceB)  { ns = 8;  R = 2048; }
  else if (avail >= 4 * sliceB)  { ns = 4;  R = 2048; }
  else if (avail >= 2 * sliceB)  { ns = 2;  R = 2048; }
  else if (avail >= 1 * sliceB)  { ns = 1;  R = 2048; }
  else if (avail >= sliceB / 2)  { ns = 1;  R = 1024; }
  else                           { ns = 1;  R = 512;  }
  int log2R = (R == 2048) ? 11 : ((R == 1024) ? 10 : 9);

  dim3 blk(256);

  // merged front: v-MFMA (256 blocks, first) + q,k exact-f32 (1024 blocks)
  proj_all<<<dim3(1280), blk, 0, stream>>>(
      q, k, v, Wq, Wk, Wv, bq, bk, bv, qh, kh, vh);

  for (int s0 = 0; s0 < B_ * H_; s0 += ns) {
    int cur = (B_ * H_ - s0) < ns ? (B_ * H_ - s0) : ns;
    for (int r0 = 0; r0 < N_; r0 += R) {
      qk128<<<dim3(R/128, N_/128, cur), blk, 0, stream>>>(qh, kh, S, s0, r0, R);
      topk_softmax_pv<<<dim3(cur * (R/4)), blk, 0, stream>>>(S, vh, pre, s0, r0, log2R);
    }
  }

  // final projection -> d_out (W split on the fly)
  gemm_mfma_final<<<dim3(BN_/128, C_/64), blk, 0, stream>>>(
      pre, Wp, bp, (float*)d_out);
}